// Round 1
// baseline (856.718 us; speedup 1.0000x reference)
//
#include <hip/hip_runtime.h>

typedef __attribute__((ext_vector_type(8))) short short8;
typedef __attribute__((ext_vector_type(4))) short short4v;
typedef __attribute__((ext_vector_type(4))) float float4v;

#define N_EDGES 640000

// RNE float -> bf16 (as raw short)
__device__ __forceinline__ short f2bf(float f) {
  union { float f; unsigned u; } a; a.f = f;
  unsigned r = a.u + 0x7FFFu + ((a.u >> 16) & 1u);
  return (short)(r >> 16);
}

__device__ __forceinline__ float fast_tanh(float x) {
  float xc = fminf(fmaxf(x, -15.f), 15.f);
  float e = __expf(2.f * xc);
  return (e - 1.f) * __builtin_amdgcn_rcpf(e + 1.f);
}

// Convert the 5 weight matrices to bf16 into ws.
// Layout (shorts): U[0..16384) V[16384..32768) P[32768..49152)
//                  W1[49152..81920) W2[81920..98304)
__global__ void prep_kernel(const float* __restrict__ U_w, const float* __restrict__ V_w,
                            const float* __restrict__ P_w, const float* __restrict__ W1,
                            const float* __restrict__ W2, short* __restrict__ ws) {
  int i = blockIdx.x * 256 + threadIdx.x;
  if (i >= 98304) return;
  float v;
  if (i < 16384)       v = U_w[i];
  else if (i < 32768)  v = V_w[i - 16384];
  else if (i < 49152)  v = P_w[i - 32768];
  else if (i < 81920)  v = W1[i - 49152];
  else                 v = W2[i - 81920];
  ws[i] = f2bf(v);
}

// Block = 64 edges. 4 waves split the N dimension (2 n-tiles each).
// LDS cut to 2 buffers (34816 B) -> 4 blocks/CU instead of 3.
// E is prefetched into registers at kernel start (leaky+cvt), committed into
// bufB after stage-1 frees it (Vdst dead). Buffer rotation:
//   bufA: Vsrc -> t -> pooled -> h1      bufB: Vdst -> Ea
__global__ __launch_bounds__(256, 4) void fused_kernel(
    const float* __restrict__ V, const float* __restrict__ E,
    const int* __restrict__ src, const int* __restrict__ dst,
    const short* __restrict__ wbf,
    const float* __restrict__ Pb, const float* __restrict__ b1,
    const float* __restrict__ b2, float* __restrict__ out) {
  __shared__ short bufA[64][136];
  __shared__ short bufB[64][136];

  const int tid  = threadIdx.x;
  const int lane = tid & 63;
  const int wave = tid >> 6;
  const int l15  = lane & 15;
  const int quad = lane >> 4;
  const int eb   = blockIdx.x * 64;
  const int n0   = wave * 2;            // this wave's first n-tile

  const short* wU  = wbf;
  const short* wV  = wbf + 16384;
  const short* wP  = wbf + 32768;
  const short* wW1 = wbf + 49152;   // [128][256]
  const short* wW2 = wbf + 81920;

  // biases for this wave's output columns
  float pb[2], b1v[2], b2v[2];
#pragma unroll
  for (int n = 0; n < 2; n++) {
    int c = (n0 + n) * 16 + l15;
    pb[n] = Pb[c]; b1v[n] = b1[c]; b2v[n] = b2[c];
  }

  // ---------- E prefetch: stream, leaky, cvt -> held in 16 VGPRs ----------
  short4v eB[8];
#pragma unroll
  for (int i = 0; i < 8; i++) {
    int idx = tid + (i << 8);        // 0..2047
    int row = idx >> 5;
    int ch  = idx & 31;
    float4v ve = __builtin_nontemporal_load(
        (const float4v*)(E + (size_t)(eb + row) * 128) + ch);
    float e0 = ve[0] > 0.f ? ve[0] : 0.01f * ve[0];
    float e1 = ve[1] > 0.f ? ve[1] : 0.01f * ve[1];
    float e2 = ve[2] > 0.f ? ve[2] : 0.01f * ve[2];
    float e3 = ve[3] > 0.f ? ve[3] : 0.01f * ve[3];
    eB[i] = (short4v){f2bf(e0), f2bf(e1), f2bf(e2), f2bf(e3)};
  }

  // ---------- staging: gather V[src], V[dst] -> LDS bf16 ----------
  for (int i = tid; i < 2048; i += 256) {   // 64 rows * 32 float4-chunks
    int row = i >> 5;
    int ch  = i & 31;
    int e   = eb + row;
    int s = src[e], d = dst[e];
    float4v vs = *((const float4v*)(V + (size_t)s * 128) + ch);
    float4v vd = *((const float4v*)(V + (size_t)d * 128) + ch);
    short4v ps = {f2bf(vs[0]), f2bf(vs[1]), f2bf(vs[2]), f2bf(vs[3])};
    short4v pd = {f2bf(vd[0]), f2bf(vd[1]), f2bf(vd[2]), f2bf(vd[3])};
    *(short4v*)&bufA[row][ch * 4] = ps;
    *(short4v*)&bufB[row][ch * 4] = pd;
  }
  __syncthreads();

  // ---------- stage 1: h_s = Vs @ U^T, h_d = Vd @ Vw^T (acc in regs) ----------
  float4v accS[4][2], accD[4][2];
#pragma unroll
  for (int m = 0; m < 4; m++)
#pragma unroll
    for (int n = 0; n < 2; n++) {
      accS[m][n] = (float4v){0.f, 0.f, 0.f, 0.f};
      accD[m][n] = (float4v){0.f, 0.f, 0.f, 0.f};
    }
#pragma unroll
  for (int kk = 0; kk < 4; kk++) {
    short8 bU[2], bV[2];
#pragma unroll
    for (int n = 0; n < 2; n++) {
      const int off = ((n0 + n) * 16 + l15) * 128 + kk * 32 + quad * 8;
      bU[n] = *(const short8*)(wU + off);
      bV[n] = *(const short8*)(wV + off);
    }
#pragma unroll
    for (int m = 0; m < 4; m++) {
      short8 aS = *(const short8*)&bufA[m * 16 + l15][kk * 32 + quad * 8];
      short8 aD = *(const short8*)&bufB[m * 16 + l15][kk * 32 + quad * 8];
#pragma unroll
      for (int n = 0; n < 2; n++) {
        accS[m][n] = __builtin_amdgcn_mfma_f32_16x16x32_bf16(aS, bU[n], accS[m][n], 0, 0, 0);
        accD[m][n] = __builtin_amdgcn_mfma_f32_16x16x32_bf16(aD, bV[n], accD[m][n], 0, 0, 0);
      }
    }
  }
  __syncthreads();   // all stage-1 LDS reads done; bufA and bufB both free

  // t = tanh(h_s * h_d) -> bufA ; commit Ea -> bufB
#pragma unroll
  for (int m = 0; m < 4; m++)
#pragma unroll
    for (int n = 0; n < 2; n++)
#pragma unroll
      for (int r = 0; r < 4; r++) {
        float t = fast_tanh(accS[m][n][r] * accD[m][n][r]);
        bufA[m * 16 + quad * 4 + r][(n0 + n) * 16 + l15] = f2bf(t);
      }
#pragma unroll
  for (int i = 0; i < 8; i++) {
    int idx = tid + (i << 8);
    int row = idx >> 5;
    int ch  = idx & 31;
    *(short4v*)&bufB[row][ch * 4] = eB[i];
  }
  __syncthreads();

  // ---------- stage 2: pooled = t @ P^T + Pb (acc in regs, then bufA) ----------
  {
    float4v accP[4][2];
#pragma unroll
    for (int m = 0; m < 4; m++)
#pragma unroll
      for (int n = 0; n < 2; n++) accP[m][n] = (float4v){0.f, 0.f, 0.f, 0.f};
#pragma unroll
    for (int kk = 0; kk < 4; kk++) {
      short8 bP[2];
#pragma unroll
      for (int n = 0; n < 2; n++)
        bP[n] = *(const short8*)(wP + ((n0 + n) * 16 + l15) * 128 + kk * 32 + quad * 8);
#pragma unroll
      for (int m = 0; m < 4; m++) {
        short8 a = *(const short8*)&bufA[m * 16 + l15][kk * 32 + quad * 8];
#pragma unroll
        for (int n = 0; n < 2; n++)
          accP[m][n] = __builtin_amdgcn_mfma_f32_16x16x32_bf16(a, bP[n], accP[m][n], 0, 0, 0);
      }
    }
    __syncthreads();   // all reads of t done; safe to overwrite bufA
#pragma unroll
    for (int m = 0; m < 4; m++)
#pragma unroll
      for (int n = 0; n < 2; n++)
#pragma unroll
        for (int r = 0; r < 4; r++)
          bufA[m * 16 + quad * 4 + r][(n0 + n) * 16 + l15] = f2bf(accP[m][n][r] + pb[n]);
  }
  __syncthreads();

  // ---------- stage 3: h1 = relu([pooled, Ea] @ W1^T + b1) ----------
  {
    float4v accH[4][2];
#pragma unroll
    for (int m = 0; m < 4; m++)
#pragma unroll
      for (int n = 0; n < 2; n++) accH[m][n] = (float4v){0.f, 0.f, 0.f, 0.f};
#pragma unroll
    for (int kk = 0; kk < 4; kk++) {   // first K-half: pooled (bufA)
      short8 bW[2];
#pragma unroll
      for (int n = 0; n < 2; n++)
        bW[n] = *(const short8*)(wW1 + ((n0 + n) * 16 + l15) * 256 + kk * 32 + quad * 8);
#pragma unroll
      for (int m = 0; m < 4; m++) {
        short8 a = *(const short8*)&bufA[m * 16 + l15][kk * 32 + quad * 8];
#pragma unroll
        for (int n = 0; n < 2; n++)
          accH[m][n] = __builtin_amdgcn_mfma_f32_16x16x32_bf16(a, bW[n], accH[m][n], 0, 0, 0);
      }
    }
#pragma unroll
    for (int kk = 0; kk < 4; kk++) {   // second K-half: Ea (bufB)
      short8 bW[2];
#pragma unroll
      for (int n = 0; n < 2; n++)
        bW[n] = *(const short8*)(wW1 + ((n0 + n) * 16 + l15) * 256 + 128 + kk * 32 + quad * 8);
#pragma unroll
      for (int m = 0; m < 4; m++) {
        short8 a = *(const short8*)&bufB[m * 16 + l15][kk * 32 + quad * 8];
#pragma unroll
        for (int n = 0; n < 2; n++)
          accH[m][n] = __builtin_amdgcn_mfma_f32_16x16x32_bf16(a, bW[n], accH[m][n], 0, 0, 0);
      }
    }
    __syncthreads();   // all reads of pooled done; safe to overwrite bufA
#pragma unroll
    for (int m = 0; m < 4; m++)
#pragma unroll
      for (int n = 0; n < 2; n++)
#pragma unroll
        for (int r = 0; r < 4; r++) {
          float v = fmaxf(accH[m][n][r] + b1v[n], 0.f);
          bufA[m * 16 + quad * 4 + r][(n0 + n) * 16 + l15] = f2bf(v);
        }
  }
  __syncthreads();

  // ---------- stage 4: out = relu(h1 @ W2^T + b2) -> global ----------
  {
    float4v accO[4][2];
#pragma unroll
    for (int m = 0; m < 4; m++)
#pragma unroll
      for (int n = 0; n < 2; n++) accO[m][n] = (float4v){0.f, 0.f, 0.f, 0.f};
#pragma unroll
    for (int kk = 0; kk < 4; kk++) {
      short8 bW[2];
#pragma unroll
      for (int n = 0; n < 2; n++)
        bW[n] = *(const short8*)(wW2 + ((n0 + n) * 16 + l15) * 128 + kk * 32 + quad * 8);
#pragma unroll
      for (int m = 0; m < 4; m++) {
        short8 a = *(const short8*)&bufA[m * 16 + l15][kk * 32 + quad * 8];
#pragma unroll
        for (int n = 0; n < 2; n++)
          accO[m][n] = __builtin_amdgcn_mfma_f32_16x16x32_bf16(a, bW[n], accO[m][n], 0, 0, 0);
      }
    }
#pragma unroll
    for (int m = 0; m < 4; m++)
#pragma unroll
      for (int n = 0; n < 2; n++)
#pragma unroll
        for (int r = 0; r < 4; r++) {
          float v = fmaxf(accO[m][n][r] + b2v[n], 0.f);
          __builtin_nontemporal_store(
              v, out + (size_t)(eb + m * 16 + quad * 4 + r) * 128 + (n0 + n) * 16 + l15);
        }
  }
}

extern "C" void kernel_launch(void* const* d_in, const int* in_sizes, int n_in,
                              void* d_out, int out_size, void* d_ws, size_t ws_size,
                              hipStream_t stream) {
  const float* V   = (const float*)d_in[0];
  const float* E   = (const float*)d_in[1];
  const int*   src = (const int*)d_in[2];
  const int*   dst = (const int*)d_in[3];
  const float* U_w = (const float*)d_in[4];
  const float* V_w = (const float*)d_in[5];
  const float* P_w = (const float*)d_in[6];
  const float* P_b = (const float*)d_in[7];
  const float* W1  = (const float*)d_in[8];
  const float* b1  = (const float*)d_in[9];
  const float* W2  = (const float*)d_in[10];
  const float* b2  = (const float*)d_in[11];
  short* ws = (short*)d_ws;

  hipLaunchKernelGGL(prep_kernel, dim3(384), dim3(256), 0, stream,
                     U_w, V_w, P_w, W1, W2, ws);
  hipLaunchKernelGGL(fused_kernel, dim3(N_EDGES / 64), dim3(256), 0, stream,
                     V, E, src, dst, ws, P_b, b1, b2, (float*)d_out);
}